// Round 3
// baseline (507.850 us; speedup 1.0000x reference)
//
#include <hip/hip_runtime.h>
#include <hip/hip_bf16.h>
#include <cstdint>

#define CDIM 256
#define KNN  16
#define BM   128

typedef __attribute__((ext_vector_type(8))) __bf16 bf16x8;
typedef __attribute__((ext_vector_type(4))) float  f4;

__device__ inline ushort f2bf(float f) {           // hardware RNE via v_cvt_pk_bf16_f32
    __bf16 b = (__bf16)f;
    return __builtin_bit_cast(ushort, b);
}
__device__ inline float bf2f(ushort h) {
    return __builtin_bit_cast(float, (unsigned int)h << 16);
}

// Convert the three 256x256 f32 weight matrices to one bf16 array [768][256].
__global__ __launch_bounds__(256)
void conv_w(const float* __restrict__ Wq, const float* __restrict__ Wk,
            const float* __restrict__ Wv, ushort* __restrict__ Wb)
{
    const int i = blockIdx.x * 256 + threadIdx.x;      // f4 index, 49152 total
    const int wsel = i >> 14;                          // / 16384
    const int off  = i & 16383;
    const float* W = wsel == 0 ? Wq : (wsel == 1 ? Wk : Wv);
    float4 v = ((const float4*)W)[off];
    ushort4 h;
    h.x = f2bf(v.x); h.y = f2bf(v.y); h.z = f2bf(v.z); h.w = f2bf(v.w);
    ((ushort4*)Wb)[i] = h;
}

// Fused QKV projection. Column-tile ct=blockIdx%6: {0,1}=Q (f32 out),
// {2,3}=K, {4,5}=V (bf16 * sens out). A-tile (128x256 f32) is converted to
// bf16 in LDS ONCE per block (full K), then 4 pure-LDS k-steps of MFMA.
// B fragments come straight from the bf16 weight array (L2-resident).
__global__ __launch_bounds__(256, 2)
void qkv_gemm(const float* __restrict__ qf, const float* __restrict__ kvf,
              const ushort* __restrict__ Wb,
              const float* __restrict__ bq, const float* __restrict__ bk,
              const float* __restrict__ bv, const float* __restrict__ sens,
              float* __restrict__ Qout, ushort* __restrict__ Kout,
              ushort* __restrict__ Vout, int M, int Npts, int nwg)
{
    __shared__ ushort As[BM * CDIM];   // 64 KB, XOR-swizzled

    // m204 bijective XCD swizzle: the 6 blocks sharing a row-tile -> same XCD
    const int orig = blockIdx.x;
    const int xcd = orig & 7, lin = orig >> 3;
    const int q8 = nwg >> 3, r8 = nwg & 7;
    const int wgid = (xcd < r8 ? xcd * (q8 + 1) : r8 * (q8 + 1) + (xcd - r8) * q8) + lin;
    const int ct    = wgid % 6;
    const int yt    = wgid / 6;
    const int tileM = yt * BM;

    const int tid  = threadIdx.x;
    const int lane = tid & 63;
    const int wid  = tid >> 6;
    const int wr   = wid >> 1, wc = wid & 1;    // 2x2 waves, 64x64 out each

    const float* Asrc = (ct < 2) ? qf : kvf;

    // ---- stage A: 128 rows x 256 cols f32 -> bf16 LDS (swizzled) ----
    if (tileM + BM <= M) {
        #pragma unroll
        for (int i = 0; i < 32; i++) {
            int idx = i * 256 + tid;            // f4 index in tile (64 per row)
            int row = idx >> 6, c4 = idx & 63;
            float4 v = *(const float4*)(Asrc + (size_t)(tileM + row) * CDIM + c4 * 4);
            ushort4 h;
            h.x = f2bf(v.x); h.y = f2bf(v.y); h.z = f2bf(v.z); h.w = f2bf(v.w);
            *(ushort4*)((char*)As + row * 512 + ((c4 * 8) ^ ((row & 7) << 4))) = h;
        }
    } else {
        #pragma unroll
        for (int i = 0; i < 32; i++) {
            int idx = i * 256 + tid;
            int row = idx >> 6, c4 = idx & 63;
            float4 v = make_float4(0.f, 0.f, 0.f, 0.f);
            if (tileM + row < M)
                v = *(const float4*)(Asrc + (size_t)(tileM + row) * CDIM + c4 * 4);
            ushort4 h;
            h.x = f2bf(v.x); h.y = f2bf(v.y); h.z = f2bf(v.z); h.w = f2bf(v.w);
            *(ushort4*)((char*)As + row * 512 + ((c4 * 8) ^ ((row & 7) << 4))) = h;
        }
    }
    __syncthreads();

    // ---- MFMA main: 4 k-steps x 2 kk, operands A from LDS, B from global ----
    f4 acc[4][4];
    #pragma unroll
    for (int i = 0; i < 4; i++)
        #pragma unroll
        for (int j = 0; j < 4; j++) acc[i][j] = (f4){0.f, 0.f, 0.f, 0.f};

    const int wbase = (ct < 2) ? 0 : (ct < 4 ? 256 : 512);   // row block in Wb
    const int c0loc = (ct & 1) * 128 + wc * 64;              // col within matrix

    #pragma unroll
    for (int ks = 0; ks < 4; ++ks) {
        #pragma unroll
        for (int kk = 0; kk < 2; ++kk) {
            bf16x8 af[4], bfr[4];
            const int kel = ks * 64 + kk * 32 + (lane >> 4) * 8;  // k element
            #pragma unroll
            for (int mi = 0; mi < 4; mi++) {
                int row = wr * 64 + mi * 16 + (lane & 15);
                int kb  = kel * 2;
                af[mi] = *(const bf16x8*)((const char*)As + row * 512 + (kb ^ ((row & 7) << 4)));
            }
            #pragma unroll
            for (int ni = 0; ni < 4; ni++) {
                int wrow = wbase + c0loc + ni * 16 + (lane & 15);
                bfr[ni] = *(const bf16x8*)(Wb + (size_t)wrow * CDIM + kel);
            }
            #pragma unroll
            for (int mi = 0; mi < 4; mi++)
                #pragma unroll
                for (int ni = 0; ni < 4; ni++)
                    acc[mi][ni] = __builtin_amdgcn_mfma_f32_16x16x32_bf16(
                        af[mi], bfr[ni], acc[mi][ni], 0, 0, 0);
        }
    }

    // ---- epilogue ----
    const float* bias = (ct < 2) ? bq : (ct < 4 ? bk : bv);
    const int r0 = tileM + wr * 64;
    #pragma unroll
    for (int ni = 0; ni < 4; ni++) {
        int col = (ct & 1) * 128 + wc * 64 + ni * 16 + (lane & 15);
        float bc = bias[col];
        #pragma unroll
        for (int mi = 0; mi < 4; mi++) {
            int rbase = r0 + mi * 16 + ((lane >> 4) << 2);  // C/D: col=lane&15, row=(lane>>4)*4+reg
            #pragma unroll
            for (int r = 0; r < 4; r++) {
                int row = rbase + r;
                if (row < M) {
                    float v = acc[mi][ni][r] + bc;
                    if (ct < 2) {
                        Qout[(size_t)row * CDIM + col] = v;
                    } else {
                        int n = row >= Npts ? row - Npts : row;
                        ushort h = f2bf(v * sens[n]);
                        (ct < 4 ? Kout : Vout)[(size_t)row * CDIM + col] = h;
                    }
                }
            }
        }
    }
}

// One wave per point: gathered 16-NN attention (bf16 K/V) + residual + LayerNorm.
__global__ __launch_bounds__(256, 4)
void attn_ln_bf(float* __restrict__ QO,
                const ushort* __restrict__ Kt, const ushort* __restrict__ Vt,
                const int* __restrict__ knn,
                const float* __restrict__ ln_g, const float* __restrict__ ln_b,
                int Ntot, int Npts)
{
    const int w = blockIdx.x * 4 + (threadIdx.x >> 6);
    if (w >= Ntot) return;
    const int lane = threadIdx.x & 63;
    const int n    = w >= Npts ? w - Npts : w;
    const size_t bofs = w >= Npts ? (size_t)Npts * CDIM : 0;

    const float4 q = *(const float4*)(QO + (size_t)w * CDIM + lane * 4);

    // knn row is wave-uniform -> force scalar loads (s_load) via readfirstlane
    const int ns = __builtin_amdgcn_readfirstlane(n);
    const int* ki = knn + ns * KNN;
    int idxs[KNN];
    #pragma unroll
    for (int j = 0; j < KNN; j++) idxs[j] = ki[j];

    float d[KNN];
    #pragma unroll
    for (int j = 0; j < KNN; j++) {
        ushort4 kv = *(const ushort4*)(Kt + bofs + (size_t)idxs[j] * CDIM + lane * 4);
        d[j] = q.x * bf2f(kv.x) + q.y * bf2f(kv.y) + q.z * bf2f(kv.z) + q.w * bf2f(kv.w);
    }
    ushort4 vr[KNN];
    #pragma unroll
    for (int j = 0; j < KNN; j++)
        vr[j] = *(const ushort4*)(Vt + bofs + (size_t)idxs[j] * CDIM + lane * 4);

    #pragma unroll
    for (int m = 1; m < 64; m <<= 1) {
        #pragma unroll
        for (int j = 0; j < KNN; j++) d[j] += __shfl_xor(d[j], m, 64);
    }

    float mx = -1e30f;
    #pragma unroll
    for (int j = 0; j < KNN; j++) { d[j] *= 0.0625f; mx = fmaxf(mx, d[j]); }
    float s = 0.f;
    #pragma unroll
    for (int j = 0; j < KNN; j++) { d[j] = __expf(d[j] - mx); s += d[j]; }
    const float inv = 1.f / s;

    float4 o = make_float4(0.f, 0.f, 0.f, 0.f);
    #pragma unroll
    for (int j = 0; j < KNN; j++) {
        const float pj = d[j] * inv;
        o.x += pj * bf2f(vr[j].x); o.y += pj * bf2f(vr[j].y);
        o.z += pj * bf2f(vr[j].z); o.w += pj * bf2f(vr[j].w);
    }

    float4 x;
    x.x = o.x + q.x; x.y = o.y + q.y; x.z = o.z + q.z; x.w = o.w + q.w;

    float ssum = x.x + x.y + x.z + x.w;
    #pragma unroll
    for (int m = 1; m < 64; m <<= 1) ssum += __shfl_xor(ssum, m, 64);
    const float mu = ssum * (1.f / 256.f);

    float4 e;
    e.x = x.x - mu; e.y = x.y - mu; e.z = x.z - mu; e.w = x.w - mu;
    float vsum = e.x * e.x + e.y * e.y + e.z * e.z + e.w * e.w;
    #pragma unroll
    for (int m = 1; m < 64; m <<= 1) vsum += __shfl_xor(vsum, m, 64);
    const float rstd = rsqrtf(vsum * (1.f / 256.f) + 1e-5f);

    const float4 g  = *(const float4*)(ln_g + lane * 4);
    const float4 bb = *(const float4*)(ln_b + lane * 4);
    float4 outv;
    outv.x = e.x * rstd * g.x + bb.x;
    outv.y = e.y * rstd * g.y + bb.y;
    outv.z = e.z * rstd * g.z + bb.z;
    outv.w = e.w * rstd * g.w + bb.w;
    *(float4*)(QO + (size_t)w * CDIM + lane * 4) = outv;
}

extern "C" void kernel_launch(void* const* d_in, const int* in_sizes, int n_in,
                              void* d_out, int out_size, void* d_ws, size_t ws_size,
                              hipStream_t stream)
{
    const float* q_feat  = (const float*)d_in[0];
    const float* kv_feat = (const float*)d_in[1];
    const int*   knn     = (const int*)d_in[2];
    const float* sens    = (const float*)d_in[3];
    const float* Wq_w    = (const float*)d_in[4];
    const float* Wq_b    = (const float*)d_in[5];
    const float* Wk_w    = (const float*)d_in[6];
    const float* Wk_b    = (const float*)d_in[7];
    const float* Wv_w    = (const float*)d_in[8];
    const float* Wv_b    = (const float*)d_in[9];
    const float* ln_g    = (const float*)d_in[10];
    const float* ln_b    = (const float*)d_in[11];

    const int Npts = in_sizes[3];              // N = 50000
    const int M    = in_sizes[0] / CDIM;       // B*N = 100000
    const int nyt  = (M + BM - 1) / BM;        // 782 row tiles
    const int Mpad = nyt * BM;

    ushort* Ktb = (ushort*)d_ws;
    ushort* Vtb = Ktb + (size_t)Mpad * CDIM;
    ushort* Wb  = Vtb + (size_t)Mpad * CDIM;   // [768][256] bf16

    conv_w<<<192, 256, 0, stream>>>(Wq_w, Wk_w, Wv_w, Wb);

    const int nwg = 6 * nyt;                   // 4692 blocks
    qkv_gemm<<<nwg, 256, 0, stream>>>(q_feat, kv_feat, Wb, Wq_b, Wk_b, Wv_b,
                                      sens, (float*)d_out, Ktb, Vtb, M, Npts, nwg);

    attn_ln_bf<<<(M + 3) / 4, 256, 0, stream>>>((float*)d_out, Ktb, Vtb, knn,
                                                ln_g, ln_b, M, Npts);
}